// Round 8
// baseline (56.869 us; speedup 1.0000x reference)
//
#include <hip/hip_runtime.h>
#include <hip/hip_bf16.h>
#include <math.h>

// Problem constants (fixed by setup_inputs): B=8, M=256, D=768, K=100
#define NROWS 2048
#define DDIM  768
#define KNEG  100
#define NLOGITS 101
#define MT 7             // ceil(101/16) M-tiles -> 112 padded logits
#define KW 6             // K-steps per wave (24 / 4 waves)

typedef __attribute__((ext_vector_type(4))) float floatx4;  // MFMA accumulator

static constexpr float TEMP_INV = 10.0f;   // 1 / 0.1
static constexpr float EPS_NORM = 1e-8f;

// pack 4 floats -> 4 fp8 e4m3 (OCP on gfx950) in a uint
__device__ __forceinline__ unsigned pack_fp8x4(float a, float b, float c, float d) {
    int u = 0;
    u = __builtin_amdgcn_cvt_pk_fp8_f32(a, b, u, false);
    u = __builtin_amdgcn_cvt_pk_fp8_f32(c, d, u, true);
    return (unsigned)u;
}

// Kernel 1: normalize target rows -> fp8 (1.5 MB; L2-resident gather source).
// One wave per row; LDS bounce to emit coalesced uint4 stores. Also zeroes
// the last-block counter used by kernel 2.
__global__ __launch_bounds__(256) void cl_prep_kernel(
        const float* __restrict__ targets,
        unsigned char* __restrict__ tn8,
        unsigned* __restrict__ counter) {
    if (blockIdx.x == 0 && threadIdx.x == 0) *counter = 0;
    const int wave = threadIdx.x >> 6, lane = threadIdx.x & 63;
    const int row = blockIdx.x * 4 + wave;
    const float4* tv = (const float4*)(targets + (size_t)row * DDIM);
    const float4 a0 = tv[2 * lane], a1 = tv[2 * lane + 1], b0 = tv[128 + lane];

    float ss = 0.f;
    ss = fmaf(a0.x, a0.x, ss); ss = fmaf(a0.y, a0.y, ss);
    ss = fmaf(a0.z, a0.z, ss); ss = fmaf(a0.w, a0.w, ss);
    ss = fmaf(a1.x, a1.x, ss); ss = fmaf(a1.y, a1.y, ss);
    ss = fmaf(a1.z, a1.z, ss); ss = fmaf(a1.w, a1.w, ss);
    ss = fmaf(b0.x, b0.x, ss); ss = fmaf(b0.y, b0.y, ss);
    ss = fmaf(b0.z, b0.z, ss); ss = fmaf(b0.w, b0.w, ss);
    #pragma unroll
    for (int off = 32; off > 0; off >>= 1) ss += __shfl_xor(ss, off);
    const float it = 1.0f / fmaxf(sqrtf(ss), EPS_NORM);

    const unsigned u0 = pack_fp8x4(a0.x * it, a0.y * it, a0.z * it, a0.w * it);
    const unsigned u1 = pack_fp8x4(a1.x * it, a1.y * it, a1.z * it, a1.w * it);
    const unsigned u2 = pack_fp8x4(b0.x * it, b0.y * it, b0.z * it, b0.w * it);

    __shared__ __align__(16) unsigned char buf[4][DDIM];
    *(uint2*)(&buf[wave][8 * lane]) = make_uint2(u0, u1);
    *(unsigned*)(&buf[wave][512 + 4 * lane]) = u2;
    __syncthreads();
    if (lane < 48)
        ((uint4*)(tn8 + (size_t)row * DDIM))[lane] = *(const uint4*)(&buf[wave][16 * lane]);
}

// Kernel 2: one block (4 waves) per pred row. Gathered fp8 target rows DMA'd
// straight to LDS via global_load_lds (linear dest, source pre-XOR-swizzled;
// A-frag ds_read applies the same XOR -> conflict-free). fp8 MFMA, 4 waves
// k-partition, wave 0 logsumexp, last finishing block does the global mean.
__global__ __launch_bounds__(256, 4) void cl_rowloss_kernel(
        const float* __restrict__ preds,
        const unsigned char* __restrict__ tn8,
        const int* __restrict__ neg_idx,
        float* __restrict__ row_loss,
        float* __restrict__ out,
        unsigned* __restrict__ counter) {
    const int i = blockIdx.x;
    const int tid = threadIdx.x;
    const int wave = tid >> 6, lane = tid & 63;

    __shared__ __align__(16) unsigned char Ab[2][16 * DDIM];  // 2 x 12 KB tiles
    __shared__ __align__(16) unsigned char pn8[DDIM];         // pred, fp8
    __shared__ __align__(16) float parts[4][MT * 16];
    __shared__ int idx_lds[MT * 16];
    __shared__ int lastflag;

    // --- gather row indices for all 112 padded logits ---
    if (tid < MT * 16)
        idx_lds[tid] = (tid == 0 || tid > KNEG) ? i : neg_idx[(size_t)i * KNEG + tid - 1];

    // --- wave 0: normalize pred row -> pn8 (fp8, LDS) ---
    if (wave == 0) {
        const float4* pv = (const float4*)(preds + (size_t)i * DDIM);
        const float4 a0 = pv[2 * lane], a1 = pv[2 * lane + 1], b0 = pv[128 + lane];
        float ss = 0.f;
        ss = fmaf(a0.x, a0.x, ss); ss = fmaf(a0.y, a0.y, ss);
        ss = fmaf(a0.z, a0.z, ss); ss = fmaf(a0.w, a0.w, ss);
        ss = fmaf(a1.x, a1.x, ss); ss = fmaf(a1.y, a1.y, ss);
        ss = fmaf(a1.z, a1.z, ss); ss = fmaf(a1.w, a1.w, ss);
        ss = fmaf(b0.x, b0.x, ss); ss = fmaf(b0.y, b0.y, ss);
        ss = fmaf(b0.z, b0.z, ss); ss = fmaf(b0.w, b0.w, ss);
        #pragma unroll
        for (int off = 32; off > 0; off >>= 1) ss += __shfl_xor(ss, off);
        const float inv = 1.0f / fmaxf(sqrtf(ss), EPS_NORM);
        *(uint2*)(&pn8[8 * lane]) = make_uint2(
            pack_fp8x4(a0.x * inv, a0.y * inv, a0.z * inv, a0.w * inv),
            pack_fp8x4(a1.x * inv, a1.y * inv, a1.z * inv, a1.w * inv));
        *(unsigned*)(&pn8[512 + 4 * lane]) =
            pack_fp8x4(b0.x * inv, b0.y * inv, b0.z * inv, b0.w * inv);
    }
    __syncthreads();

    // --- staging: 768 x 16B chunks per tile, DMA direct to LDS.
    // LDS dest linear (chunk g at byte 16g); source chunk pre-swizzled
    // (c ^ (row&7)) so that swizzled ds_reads below see logical data.
    auto stage = [&](int t, int buf) {
        #pragma unroll
        for (int it = 0; it < 3; ++it) {
            const int g = wave * 192 + it * 64 + lane;   // 0..767
            const int r = g / 48, c = g - r * 48;        // row-in-tile, chunk
            const unsigned char* src = tn8 + (size_t)idx_lds[t * 16 + r] * DDIM
                                       + ((c ^ (r & 7)) << 4);
            __builtin_amdgcn_global_load_lds(
                (const __attribute__((address_space(1))) void*)src,
                (__attribute__((address_space(3))) void*)&Ab[buf][(wave * 192 + it * 64) << 4],
                16, 0, 0);
        }
    };

    // --- B-frags (pred) hoisted to registers: 6 x 8 fp8 per wave ---
    const int kb = wave * KW;
    const int q = lane >> 4;
    long long bfr[KW];
    #pragma unroll
    for (int kk = 0; kk < KW; ++kk)
        bfr[kk] = *(const long long*)(&pn8[(kb + kk) * 32 + q * 8]);

    // A-frag addressing: row = lane&15, swizzle XOR on byte bits 4-6
    const int aoff = (lane & 15) * DDIM + kb * 32 + q * 8;
    const int axor = (lane & 7) << 4;

    stage(0, 0);
    __syncthreads();   // drains vmcnt -> tile 0 resident

    floatx4 acc[MT] = {};
    #pragma unroll
    for (int t = 0; t < MT; ++t) {
        if (t < MT - 1) stage(t + 1, (t + 1) & 1);     // async, in flight
        const int cur = t & 1;
        #pragma unroll
        for (int kk = 0; kk < KW; ++kk) {
            const long long af = *(const long long*)(&Ab[cur][(aoff + kk * 32) ^ axor]);
            acc[t] = __builtin_amdgcn_mfma_f32_16x16x32_fp8_fp8(af, bfr[kk],
                                                                acc[t], 0, 0, 0);
        }
        __syncthreads();   // vmcnt(0) drain: tile t+1 staged
    }

    // --- per-wave partial dots -> LDS. C/D map: col=lane&15, row=(lane>>4)*4+reg ---
    if ((lane & 15) == 0) {
        const int rb = q * 4;
        #pragma unroll
        for (int t = 0; t < MT; ++t)
            *(floatx4*)(&parts[wave][t * 16 + rb]) = acc[t];
    }
    __syncthreads();

    // --- wave 0: combine 4 k-partials, logsumexp, agent-scope store ---
    if (wave == 0) {
        const float v0 = (parts[0][lane] + parts[1][lane] +
                          parts[2][lane] + parts[3][lane]) * TEMP_INV;
        float v1 = -INFINITY;
        if (lane <= NLOGITS - 65)
            v1 = (parts[0][64 + lane] + parts[1][64 + lane] +
                  parts[2][64 + lane] + parts[3][64 + lane]) * TEMP_INV;
        const float l0 = __shfl(v0, 0);
        float m = fmaxf(v0, v1);
        #pragma unroll
        for (int off = 32; off > 0; off >>= 1) m = fmaxf(m, __shfl_xor(m, off));
        float e = expf(v0 - m);
        if (lane <= NLOGITS - 65) e += expf(v1 - m);
        #pragma unroll
        for (int off = 32; off > 0; off >>= 1) e += __shfl_xor(e, off);
        if (lane == 0)
            __hip_atomic_store(&row_loss[i], (m + logf(e)) - l0,
                               __ATOMIC_RELAXED, __HIP_MEMORY_SCOPE_AGENT);
    }

    // --- last-block deterministic mean over the 2048 row losses ---
    if (tid == 0) {
        __threadfence();
        lastflag = (atomicAdd(counter, 1u) == NROWS - 1);
    }
    __syncthreads();
    if (lastflag) {
        __threadfence();
        float s = 0.f;
        #pragma unroll
        for (int c = 0; c < 2; ++c) {
            const float4 v = ((const float4*)row_loss)[tid + 256 * c];
            s += (v.x + v.y) + (v.z + v.w);
        }
        #pragma unroll
        for (int off = 32; off > 0; off >>= 1) s += __shfl_down(s, off);
        __shared__ float sw[4];
        if ((tid & 63) == 0) sw[tid >> 6] = s;
        __syncthreads();
        if (tid == 0) out[0] = (sw[0] + sw[1] + sw[2] + sw[3]) / (float)NROWS;
    }
}

extern "C" void kernel_launch(void* const* d_in, const int* in_sizes, int n_in,
                              void* d_out, int out_size, void* d_ws, size_t ws_size,
                              hipStream_t stream) {
    const float* preds   = (const float*)d_in[0];
    const float* targets = (const float*)d_in[1];
    const int*   neg_idx = (const int*)d_in[2];
    float* out = (float*)d_out;

    // workspace: tn8 (1.5 MB) | row_loss[2048] | counter
    unsigned char* tn8 = (unsigned char*)d_ws;
    float* row_loss = (float*)((char*)d_ws + (size_t)NROWS * DDIM);
    unsigned* counter = (unsigned*)(row_loss + NROWS);

    cl_prep_kernel<<<NROWS / 4, 256, 0, stream>>>(targets, tn8, counter);
    cl_rowloss_kernel<<<NROWS, 256, 0, stream>>>(preds, tn8, neg_idx,
                                                 row_loss, out, counter);
}

// Round 9
// 24.943 us; speedup vs baseline: 2.2800x; 2.2800x over previous
//
#include <hip/hip_runtime.h>
#include <hip/hip_bf16.h>
#include <math.h>

// Problem constants (fixed by setup_inputs): B=8, M=256, D=768, K=100
#define NROWS 2048
#define DDIM  768
#define KNEG  100
#define NLOGITS 101
#define MT 7             // ceil(101/16) M-tiles -> 112 padded logits
#define KW 6             // K-steps per wave (24 / 4 waves)

typedef __attribute__((ext_vector_type(4))) float floatx4;  // MFMA accumulator

static constexpr float TEMP_INV = 10.0f;   // 1 / 0.1
static constexpr float EPS_NORM = 1e-8f;

// pack 4 floats -> 4 fp8 e4m3 (OCP on gfx950) in a uint
__device__ __forceinline__ unsigned pack_fp8x4(float a, float b, float c, float d) {
    int u = 0;
    u = __builtin_amdgcn_cvt_pk_fp8_f32(a, b, u, false);
    u = __builtin_amdgcn_cvt_pk_fp8_f32(c, d, u, true);
    return (unsigned)u;
}

// Kernel 1: normalize target rows -> fp8 (1.5 MB; L2-resident gather source).
// One wave per row; LDS bounce to emit coalesced uint4 stores.
__global__ __launch_bounds__(256) void cl_prep_kernel(
        const float* __restrict__ targets,
        unsigned char* __restrict__ tn8) {
    const int wave = threadIdx.x >> 6, lane = threadIdx.x & 63;
    const int row = blockIdx.x * 4 + wave;
    const float4* tv = (const float4*)(targets + (size_t)row * DDIM);
    const float4 a0 = tv[2 * lane], a1 = tv[2 * lane + 1], b0 = tv[128 + lane];

    float ss = 0.f;
    ss = fmaf(a0.x, a0.x, ss); ss = fmaf(a0.y, a0.y, ss);
    ss = fmaf(a0.z, a0.z, ss); ss = fmaf(a0.w, a0.w, ss);
    ss = fmaf(a1.x, a1.x, ss); ss = fmaf(a1.y, a1.y, ss);
    ss = fmaf(a1.z, a1.z, ss); ss = fmaf(a1.w, a1.w, ss);
    ss = fmaf(b0.x, b0.x, ss); ss = fmaf(b0.y, b0.y, ss);
    ss = fmaf(b0.z, b0.z, ss); ss = fmaf(b0.w, b0.w, ss);
    #pragma unroll
    for (int off = 32; off > 0; off >>= 1) ss += __shfl_xor(ss, off);
    const float it = 1.0f / fmaxf(sqrtf(ss), EPS_NORM);

    const unsigned u0 = pack_fp8x4(a0.x * it, a0.y * it, a0.z * it, a0.w * it);
    const unsigned u1 = pack_fp8x4(a1.x * it, a1.y * it, a1.z * it, a1.w * it);
    const unsigned u2 = pack_fp8x4(b0.x * it, b0.y * it, b0.z * it, b0.w * it);

    __shared__ __align__(16) unsigned char buf[4][DDIM];
    *(uint2*)(&buf[wave][8 * lane]) = make_uint2(u0, u1);
    *(unsigned*)(&buf[wave][512 + 4 * lane]) = u2;
    __syncthreads();
    if (lane < 48)
        ((uint4*)(tn8 + (size_t)row * DDIM))[lane] = *(const uint4*)(&buf[wave][16 * lane]);
}

// Kernel 2: one block (4 waves) per pred row. Gathered fp8 target rows DMA'd
// straight to LDS via global_load_lds (linear dest, source pre-XOR-swizzled;
// A-frag ds_read applies the same XOR -> near-conflict-free). fp8 MFMA,
// 4 waves k-partition, partials combined via LDS, wave 0 logsumexp.
__global__ __launch_bounds__(256, 4) void cl_rowloss_kernel(
        const float* __restrict__ preds,
        const unsigned char* __restrict__ tn8,
        const int* __restrict__ neg_idx,
        float* __restrict__ row_loss) {
    const int i = blockIdx.x;
    const int tid = threadIdx.x;
    const int wave = tid >> 6, lane = tid & 63;

    __shared__ __align__(16) unsigned char Ab[2][16 * DDIM];  // 2 x 12 KB tiles
    __shared__ __align__(16) unsigned char pn8[DDIM];         // pred, fp8
    __shared__ __align__(16) float parts[4][MT * 16];
    __shared__ int idx_lds[MT * 16];

    // --- gather row indices for all 112 padded logits ---
    if (tid < MT * 16)
        idx_lds[tid] = (tid == 0 || tid > KNEG) ? i : neg_idx[(size_t)i * KNEG + tid - 1];
    __syncthreads();

    // --- staging: 768 x 16B chunks per tile, DMA direct to LDS.
    // LDS dest linear (chunk g at byte 16g); source chunk pre-swizzled
    // (c ^ (r&7)) so the swizzled ds_reads below see logical data.
    auto stage = [&](int t, int buf) {
        #pragma unroll
        for (int it = 0; it < 3; ++it) {
            const int g = wave * 192 + it * 64 + lane;   // 0..767
            const int r = g / 48, c = g - r * 48;        // row-in-tile, chunk
            const unsigned char* src = tn8 + (size_t)idx_lds[t * 16 + r] * DDIM
                                       + ((c ^ (r & 7)) << 4);
            __builtin_amdgcn_global_load_lds(
                (const __attribute__((address_space(1))) void*)src,
                (__attribute__((address_space(3))) void*)&Ab[buf][(wave * 192 + it * 64) << 4],
                16, 0, 0);
        }
    };

    // Tile 0 loads go in flight NOW; their latency hides under the pred
    // normalize/pack VALU work below. Barrier after drains vmcnt.
    stage(0, 0);

    // --- wave 0: normalize pred row -> pn8 (fp8, LDS) ---
    if (wave == 0) {
        const float4* pv = (const float4*)(preds + (size_t)i * DDIM);
        const float4 a0 = pv[2 * lane], a1 = pv[2 * lane + 1], b0 = pv[128 + lane];
        float ss = 0.f;
        ss = fmaf(a0.x, a0.x, ss); ss = fmaf(a0.y, a0.y, ss);
        ss = fmaf(a0.z, a0.z, ss); ss = fmaf(a0.w, a0.w, ss);
        ss = fmaf(a1.x, a1.x, ss); ss = fmaf(a1.y, a1.y, ss);
        ss = fmaf(a1.z, a1.z, ss); ss = fmaf(a1.w, a1.w, ss);
        ss = fmaf(b0.x, b0.x, ss); ss = fmaf(b0.y, b0.y, ss);
        ss = fmaf(b0.z, b0.z, ss); ss = fmaf(b0.w, b0.w, ss);
        #pragma unroll
        for (int off = 32; off > 0; off >>= 1) ss += __shfl_xor(ss, off);
        const float inv = 1.0f / fmaxf(sqrtf(ss), EPS_NORM);
        *(uint2*)(&pn8[8 * lane]) = make_uint2(
            pack_fp8x4(a0.x * inv, a0.y * inv, a0.z * inv, a0.w * inv),
            pack_fp8x4(a1.x * inv, a1.y * inv, a1.z * inv, a1.w * inv));
        *(unsigned*)(&pn8[512 + 4 * lane]) =
            pack_fp8x4(b0.x * inv, b0.y * inv, b0.z * inv, b0.w * inv);
    }
    __syncthreads();   // pn8 ready + tile 0 resident (vmcnt drained)

    // --- B-frags (pred) hoisted to registers: 6 x 8 fp8 per wave ---
    const int kb = wave * KW;
    const int q = lane >> 4;
    long long bfr[KW];
    #pragma unroll
    for (int kk = 0; kk < KW; ++kk)
        bfr[kk] = *(const long long*)(&pn8[(kb + kk) * 32 + q * 8]);

    // A-frag addressing: row = lane&15, swizzle XOR on byte bits 4-6
    const int aoff = (lane & 15) * DDIM + kb * 32 + q * 8;
    const int axor = (lane & 7) << 4;

    floatx4 acc[MT] = {};
    #pragma unroll
    for (int t = 0; t < MT; ++t) {
        if (t < MT - 1) stage(t + 1, (t + 1) & 1);     // async, in flight
        const int cur = t & 1;
        #pragma unroll
        for (int kk = 0; kk < KW; ++kk) {
            const long long af = *(const long long*)(&Ab[cur][(aoff + kk * 32) ^ axor]);
            acc[t] = __builtin_amdgcn_mfma_f32_16x16x32_fp8_fp8(af, bfr[kk],
                                                                acc[t], 0, 0, 0);
        }
        __syncthreads();   // vmcnt(0) drain: tile t+1 staged
    }

    // --- per-wave partial dots -> LDS. C/D map: col=lane&15, row=(lane>>4)*4+reg ---
    if ((lane & 15) == 0) {
        const int rb = q * 4;
        #pragma unroll
        for (int t = 0; t < MT; ++t)
            *(floatx4*)(&parts[wave][t * 16 + rb]) = acc[t];
    }
    __syncthreads();

    // --- wave 0: combine 4 k-partials, logsumexp over logits[0..100] ---
    if (wave == 0) {
        const float v0 = (parts[0][lane] + parts[1][lane] +
                          parts[2][lane] + parts[3][lane]) * TEMP_INV;
        float v1 = -INFINITY;
        if (lane <= NLOGITS - 65)
            v1 = (parts[0][64 + lane] + parts[1][64 + lane] +
                  parts[2][64 + lane] + parts[3][64 + lane]) * TEMP_INV;
        const float l0 = __shfl(v0, 0);
        float m = fmaxf(v0, v1);
        #pragma unroll
        for (int off = 32; off > 0; off >>= 1) m = fmaxf(m, __shfl_xor(m, off));
        float e = expf(v0 - m);
        if (lane <= NLOGITS - 65) e += expf(v1 - m);
        #pragma unroll
        for (int off = 32; off > 0; off >>= 1) e += __shfl_xor(e, off);
        if (lane == 0) row_loss[i] = (m + logf(e)) - l0;
    }
}

// Kernel 3: deterministic final mean over the 2048 row losses.
__global__ void cl_reduce_kernel(const float* __restrict__ row_loss,
                                 float* __restrict__ out) {
    const int tid = threadIdx.x; // 256
    float s = 0.f;
    #pragma unroll
    for (int c = 0; c < 2; ++c) {
        const float4 v = ((const float4*)row_loss)[tid + 256 * c];
        s += (v.x + v.y) + (v.z + v.w);
    }
    #pragma unroll
    for (int off = 32; off > 0; off >>= 1) s += __shfl_down(s, off);
    __shared__ float sw[4];
    const int wave = tid >> 6, lane = tid & 63;
    if (lane == 0) sw[wave] = s;
    __syncthreads();
    if (tid == 0) out[0] = (sw[0] + sw[1] + sw[2] + sw[3]) / (float)NROWS;
}

extern "C" void kernel_launch(void* const* d_in, const int* in_sizes, int n_in,
                              void* d_out, int out_size, void* d_ws, size_t ws_size,
                              hipStream_t stream) {
    const float* preds   = (const float*)d_in[0];
    const float* targets = (const float*)d_in[1];
    const int*   neg_idx = (const int*)d_in[2];
    float* out = (float*)d_out;

    // workspace: tn8 (1.5 MB) | row_loss[2048]
    unsigned char* tn8 = (unsigned char*)d_ws;
    float* row_loss = (float*)((char*)d_ws + (size_t)NROWS * DDIM);

    cl_prep_kernel<<<NROWS / 4, 256, 0, stream>>>(targets, tn8);
    cl_rowloss_kernel<<<NROWS, 256, 0, stream>>>(preds, tn8, neg_idx, row_loss);
    cl_reduce_kernel<<<1, 256, 0, stream>>>(row_loss, out);
}